// Round 5
// baseline (196.502 us; speedup 1.0000x reference)
//
#include <hip/hip_runtime.h>
#include <math.h>

#define NP 16384
#define NG 2048
#define NC 17
#define FPS 40      // floats per primitive in fp table

#define NVX 200
#define NVY 200
#define NVZ 16
#define NVOX (NVX * NVY * NVZ)
#define CAP 64      // max primitives listed per voxel (expected max ~18)

#define GRIDSZ 0.4f
#define PCMINX -40.0f
#define PCMINY -40.0f
#define PCMINZ -1.0f
#define SCALE_MULTC 3.0f

// fp layout per primitive (40 floats, 160 B, 16B-aligned):
// [0:3]  murot_i = sum_j mu_j * rot[j*3+i]
// [3:12] rot (row-major)
// [12:15] 1/scales
// [15] opa, [16] 1/u, [17] 1/v, [18] v/u, [19] pad
// [20:37] semantics row, [37:40] pad
//
// fill_kernel: one block per primitive. Builds the fp row (threads 0..39) and
// scatters the primitive index into every voxel of its clipped Chebyshev
// footprint. Membership test "cheb(point_voxel, mean_voxel) <= rad" is EXACTLY
// "point_voxel inside this footprint", so gather needs no further filtering.
// NOTE: list entry order depends on atomic arrival order (run-to-run fp-sum
// jitter ~1e-6, far under the 8.3e-2 absmax threshold); the SET of entries is
// deterministic.
__global__ __launch_bounds__(128)
void fill_kernel(const float* __restrict__ means3D, const float* __restrict__ opas,
                 const float* __restrict__ uu, const float* __restrict__ vv,
                 const float* __restrict__ scales, const float* __restrict__ rot3D,
                 const float* __restrict__ semantics,
                 unsigned int* __restrict__ cnt, unsigned short* __restrict__ list,
                 float* __restrict__ fp) {
    int g = blockIdx.x;
    int tid = threadIdx.x;
    float mx = means3D[g * 3 + 0], my = means3D[g * 3 + 1], mz = means3D[g * 3 + 2];
    float scx = scales[g * 3 + 0], scy = scales[g * 3 + 1], scz = scales[g * 3 + 2];

    // fp row (threads 0..39)
    float* o = fp + (size_t)g * FPS;
    if (tid < 3) {
        o[tid] = mx * rot3D[g * 9 + 0 + tid] + my * rot3D[g * 9 + 3 + tid] +
                 mz * rot3D[g * 9 + 6 + tid];
    } else if (tid < 12) {
        o[tid] = rot3D[g * 9 + tid - 3];
    } else if (tid < 15) {
        float s = (tid == 12) ? scx : (tid == 13) ? scy : scz;
        o[tid] = 1.0f / s;
    } else if (tid == 15) {
        o[15] = opas[g];
    } else if (tid == 16) {
        o[16] = 1.0f / uu[g];
    } else if (tid == 17) {
        o[17] = 1.0f / vv[g];
    } else if (tid == 18) {
        o[18] = vv[g] / uu[g];
    } else if (tid == 19) {
        o[19] = 0.0f;
    } else if (tid < 37) {
        o[tid] = semantics[(size_t)g * NC + (tid - 20)];
    } else if (tid < 40) {
        o[tid] = 0.0f;
    }

    // footprint scatter
    int vx = (int)floorf((mx - PCMINX) / GRIDSZ);
    int vy = (int)floorf((my - PCMINY) / GRIDSZ);
    int vz = (int)floorf((mz - PCMINZ) / GRIDSZ);
    float smax = fmaxf(scx, fmaxf(scy, scz));
    int rad = (int)ceilf(smax * SCALE_MULTC / GRIDSZ);
    if (rad < 1) rad = 1;
    int lx = max(vx - rad, 0), hx = min(vx + rad, NVX - 1);
    int ly = max(vy - rad, 0), hy = min(vy + rad, NVY - 1);
    int lz = max(vz - rad, 0), hz = min(vz + rad, NVZ - 1);
    int spanY = hy - ly + 1;
    int cols = (hx - lx + 1) * spanY;   // <= 121

    for (int t = tid; t < cols; t += 128) {
        int x = lx + t / spanY;
        int y = ly + t % spanY;
        int base = (x * NVY + y) * NVZ;
        for (int z = lz; z <= hz; ++z) {
            int v = base + z;
            unsigned r = atomicAdd(&cnt[v], 1u);
            if (r < CAP) list[(size_t)v * CAP + r] = (unsigned short)g;
        }
    }
}

__device__ __forceinline__ void hit_accum(const float* __restrict__ fp, int g,
                                          float px, float py, float pz,
                                          float* acc, float& density, float& logbin) {
    const float4* q = (const float4*)(fp + (size_t)g * FPS);
    float4 q0 = q[0], q1 = q[1], q2 = q[2], q3 = q[3], q4 = q[4];
    float l0 = px * q0.w + py * q1.z + pz * q2.y - q0.x;
    float l1 = px * q1.x + py * q1.w + pz * q2.z - q0.y;
    float l2 = px * q1.y + py * q2.x + pz * q2.w - q0.z;
    float t0 = l0 * q3.x, t1 = l1 * q3.y, t2 = l2 * q3.z;
    float s0 = t0 * t0 + 1e-8f;
    float s1 = t1 * t1 + 1e-8f;
    float s2 = t2 * t2 + 1e-8f;
    float f = __powf(__powf(s0, q4.y) + __powf(s1, q4.y), q4.z) + __powf(s2, q4.x);
    float a = q3.w * __expf(-0.5f * f);
    density += a;
    float sem[NC];
    *(float4*)(sem + 0)  = q[5];
    *(float4*)(sem + 4)  = q[6];
    *(float4*)(sem + 8)  = q[7];
    *(float4*)(sem + 12) = q[8];
    sem[16] = fp[(size_t)g * FPS + 36];
#pragma unroll
    for (int c = 0; c < NC; ++c) acc[c] = fmaf(a, sem[c], acc[c]);
    logbin += __logf(1.0f - fminf(a, 1.0f - 1e-4f));
}

// 1 thread per point: read own voxel's candidate list (avg ~3), accumulate, write.
__global__ __launch_bounds__(64)
void gather_kernel(const float* __restrict__ pts,
                   const unsigned int* __restrict__ cnt,
                   const unsigned short* __restrict__ list,
                   const float* __restrict__ fp,
                   float* __restrict__ out) {
    int p = blockIdx.x * 64 + threadIdx.x;
    float px = pts[p * 3 + 0], py = pts[p * 3 + 1], pz = pts[p * 3 + 2];
    int ix = (int)floorf((px - PCMINX) / GRIDSZ);
    int iy = (int)floorf((py - PCMINY) / GRIDSZ);
    int iz = (int)floorf((pz - PCMINZ) / GRIDSZ);
    int v = (ix * NVY + iy) * NVZ + iz;

    int n = (int)min(cnt[v], (unsigned)CAP);
    const unsigned short* lst = list + (size_t)v * CAP;

    float density = 0.0f, logbin = 0.0f;
    float acc[NC];
#pragma unroll
    for (int c = 0; c < NC; ++c) acc[c] = 0.0f;

    for (int k = 0; k < n; ++k) {
        int g = lst[k];
        hit_accum(fp, g, px, py, pz, acc, density, logbin);
    }

    float inv = 1.0f / (density + 1e-9f);
#pragma unroll
    for (int c = 0; c < NC; ++c) out[(size_t)p * NC + c] = acc[c] * inv;
    out[(size_t)NP * NC + p] = 1.0f - expf(logbin);
    out[(size_t)NP * NC + NP + p] = density;
}

// ---- fallback (ws too small): monolithic kernel ----
__global__ __launch_bounds__(64)
void agg_kernel_fb(const float* __restrict__ pts,
                   const float* __restrict__ means3D,
                   const float* __restrict__ opas,
                   const float* __restrict__ uu,
                   const float* __restrict__ vv,
                   const float* __restrict__ semantics,
                   const float* __restrict__ scales,
                   const float* __restrict__ rot3D,
                   float* __restrict__ out) {
    int p = blockIdx.x * 64 + threadIdx.x;
    if (p >= NP) return;
    float px = pts[p * 3 + 0], py = pts[p * 3 + 1], pz = pts[p * 3 + 2];
    int pix = (int)floorf((px - PCMINX) / GRIDSZ);
    int piy = (int)floorf((py - PCMINY) / GRIDSZ);
    int piz = (int)floorf((pz - PCMINZ) / GRIDSZ);
    float density = 0.0f, logbin = 0.0f;
    float acc[NC];
#pragma unroll
    for (int c = 0; c < NC; ++c) acc[c] = 0.0f;
    for (int g = 0; g < NG; ++g) {
        float cx = means3D[g * 3 + 0], cy = means3D[g * 3 + 1], cz = means3D[g * 3 + 2];
        int mx = (int)floorf((cx - PCMINX) / GRIDSZ);
        int my = (int)floorf((cy - PCMINY) / GRIDSZ);
        int mz = (int)floorf((cz - PCMINZ) / GRIDSZ);
        float smax = fmaxf(scales[g * 3 + 0], fmaxf(scales[g * 3 + 1], scales[g * 3 + 2]));
        int rad = (int)ceilf(smax * SCALE_MULTC / GRIDSZ);
        rad = rad < 1 ? 1 : rad;
        int cheb = max(abs(pix - mx), max(abs(piy - my), abs(piz - mz)));
        if (cheb <= rad) {
            const float* r = rot3D + (size_t)g * 9;
            float dx = px - cx, dy = py - cy, dz = pz - cz;
            float l0 = dx * r[0] + dy * r[3] + dz * r[6];
            float l1 = dx * r[1] + dy * r[4] + dz * r[7];
            float l2 = dx * r[2] + dy * r[5] + dz * r[8];
            float t0 = l0 / scales[g * 3 + 0], t1 = l1 / scales[g * 3 + 1], t2 = l2 / scales[g * 3 + 2];
            float s0 = t0 * t0 + 1e-8f, s1 = t1 * t1 + 1e-8f, s2 = t2 * t2 + 1e-8f;
            float ie1 = 1.0f / uu[g], ie2 = 1.0f / vv[g], e21 = vv[g] / uu[g];
            float f = powf(powf(s0, ie2) + powf(s1, ie2), e21) + powf(s2, ie1);
            float a = opas[g] * expf(-0.5f * f);
            density += a;
            const float* sg = semantics + (size_t)g * NC;
#pragma unroll
            for (int c = 0; c < NC; ++c) acc[c] = fmaf(a, sg[c], acc[c]);
            logbin += log1pf(-fminf(a, 1.0f - 1e-4f));
        }
    }
    float inv = 1.0f / (density + 1e-9f);
#pragma unroll
    for (int c = 0; c < NC; ++c) out[(size_t)p * NC + c] = acc[c] * inv;
    out[(size_t)NP * NC + p] = 1.0f - expf(logbin);
    out[(size_t)NP * NC + NP + p] = density;
}

extern "C" void kernel_launch(void* const* d_in, const int* in_sizes, int n_in,
                              void* d_out, int out_size, void* d_ws, size_t ws_size,
                              hipStream_t stream) {
    const float* pts       = (const float*)d_in[0];
    const float* means3D   = (const float*)d_in[1];
    const float* opas      = (const float*)d_in[2];
    const float* uu        = (const float*)d_in[3];
    const float* vv        = (const float*)d_in[4];
    const float* semantics = (const float*)d_in[5];
    const float* scales    = (const float*)d_in[6];
    const float* rot3D     = (const float*)d_in[7];
    float* out = (float*)d_out;

    size_t fpBytes   = (size_t)NG * FPS * sizeof(float);          // 327,680
    size_t cntOff    = fpBytes;                                   // 4B-aligned
    size_t cntBytes  = (size_t)NVOX * sizeof(unsigned int);       // 2,560,000
    size_t listOff   = (cntOff + cntBytes + 15) & ~(size_t)15;
    size_t listBytes = (size_t)NVOX * CAP * sizeof(unsigned short); // 81,920,000
    size_t need = listOff + listBytes;                            // ~84.8 MB

    if (ws_size >= need) {
        float* fp = (float*)d_ws;
        unsigned int* cnt = (unsigned int*)((char*)d_ws + cntOff);
        unsigned short* list = (unsigned short*)((char*)d_ws + listOff);
        hipMemsetAsync(cnt, 0, cntBytes, stream);
        fill_kernel<<<NG, 128, 0, stream>>>(means3D, opas, uu, vv, scales, rot3D,
                                            semantics, cnt, list, fp);
        gather_kernel<<<NP / 64, 64, 0, stream>>>(pts, cnt, list, fp, out);
    } else {
        agg_kernel_fb<<<NP / 64, 64, 0, stream>>>(pts, means3D, opas, uu, vv, semantics,
                                                  scales, rot3D, out);
    }
}

// Round 6
// 49.232 us; speedup vs baseline: 3.9913x; 3.9913x over previous
//
#include <hip/hip_runtime.h>
#include <math.h>

#define NP 16384
#define NG 2048
#define NC 17
#define FPS 40      // floats per primitive in fp table

#define NVX 200
#define NVY 200
#define NVZ 16
#define TSH 3       // tile = 8x8 voxels in (x,y)
#define NTX 25
#define NTY 25
#define NTILE (NTX * NTY)
#define TCAP 128    // max prims per tile list (expected max ~25-40)

#define GRIDSZ 0.4f
#define PCMINX -40.0f
#define PCMINY -40.0f
#define PCMINZ -1.0f
#define SCALE_MULTC 3.0f

// fp layout per primitive (40 floats, 160 B, 16B-aligned):
// [0:3]  murot_i = sum_j mu_j * rot[j*3+i]
// [3:12] rot (row-major)
// [12:15] 1/scales
// [15] opa, [16] 1/u, [17] 1/v, [18] v/u, [19] pad
// [20:37] semantics row, [37:40] pad
// aabb: per-prim voxel AABB packed (lo | hi<<16) per axis; membership test
// "cheb(point_voxel, mean_voxel) <= rad" == "point_voxel inside AABB".
__global__ __launch_bounds__(64)
void prep_kernel(const float* __restrict__ means3D, const float* __restrict__ opas,
                 const float* __restrict__ uu, const float* __restrict__ vv,
                 const float* __restrict__ scales, const float* __restrict__ rot3D,
                 const float* __restrict__ semantics,
                 int4* __restrict__ aabb, float* __restrict__ fp) {
    int g = blockIdx.x * 64 + threadIdx.x;
    if (g >= NG) return;
    float mx = means3D[g * 3 + 0], my = means3D[g * 3 + 1], mz = means3D[g * 3 + 2];
    float sx = scales[g * 3 + 0], sy = scales[g * 3 + 1], sz = scales[g * 3 + 2];
    int vx = (int)floorf((mx - PCMINX) / GRIDSZ);
    int vy = (int)floorf((my - PCMINY) / GRIDSZ);
    int vz = (int)floorf((mz - PCMINZ) / GRIDSZ);
    float smax = fmaxf(sx, fmaxf(sy, sz));
    int rad = (int)ceilf(smax * SCALE_MULTC / GRIDSZ);
    if (rad < 1) rad = 1;
    int4 b;
    b.x = max(vx - rad, 0) | ((vx + rad) << 16);
    b.y = max(vy - rad, 0) | ((vy + rad) << 16);
    b.z = max(vz - rad, 0) | ((vz + rad) << 16);
    b.w = 0;
    aabb[g] = b;

    float r[9];
#pragma unroll
    for (int i = 0; i < 9; ++i) r[i] = rot3D[g * 9 + i];
    float row[FPS];
    row[0] = mx * r[0] + my * r[3] + mz * r[6];
    row[1] = mx * r[1] + my * r[4] + mz * r[7];
    row[2] = mx * r[2] + my * r[5] + mz * r[8];
#pragma unroll
    for (int i = 0; i < 9; ++i) row[3 + i] = r[i];
    row[12] = 1.0f / sx; row[13] = 1.0f / sy; row[14] = 1.0f / sz;
    row[15] = opas[g];
    row[16] = 1.0f / uu[g];
    row[17] = 1.0f / vv[g];
    row[18] = vv[g] / uu[g];
    row[19] = 0.0f;
#pragma unroll
    for (int c = 0; c < NC; ++c) row[20 + c] = semantics[(size_t)g * NC + c];
    row[37] = 0.0f; row[38] = 0.0f; row[39] = 0.0f;

    float4* o = (float4*)(fp + (size_t)g * FPS);
#pragma unroll
    for (int j = 0; j < FPS / 4; ++j) o[j] = *(const float4*)(row + 4 * j);
}

// One wave per tile: scan all prim AABBs, ballot-compact overlapping prims in
// ascending-g order (deterministic, no atomics, no memset needed).
__global__ __launch_bounds__(64)
void tile_kernel(const int4* __restrict__ aabb,
                 unsigned int* __restrict__ cnt,
                 unsigned short* __restrict__ list) {
    int t = blockIdx.x;
    int lane = threadIdx.x;
    int tx = t % NTX, ty = t / NTX;
    unsigned short* lst = list + (size_t)t * TCAP;
    unsigned cl = 0;
    for (int base = 0; base < NG; base += 64) {
        int4 b = aabb[base + lane];
        int xlo = (b.x & 0xffff) >> TSH, xhi = b.x >> (16 + TSH);
        int ylo = (b.y & 0xffff) >> TSH, yhi = b.y >> (16 + TSH);
        bool ov = (xlo <= tx) & (xhi >= tx) & (ylo <= ty) & (yhi >= ty);
        unsigned long long bal = __ballot(ov);
        if (ov) {
            int pos = cl + (int)__popcll(bal & ((1ull << lane) - 1ull));
            if (pos < TCAP) lst[pos] = (unsigned short)(base + lane);
        }
        cl += (unsigned)__popcll(bal);
    }
    if (lane == 0) cnt[t] = min(cl, (unsigned)TCAP);
}

__device__ __forceinline__ void hit_accum(const float* __restrict__ fp, int g,
                                          float px, float py, float pz,
                                          float* acc, float& density, float& logbin) {
    const float4* q = (const float4*)(fp + (size_t)g * FPS);
    float4 q0 = q[0], q1 = q[1], q2 = q[2], q3 = q[3], q4 = q[4];
    float l0 = px * q0.w + py * q1.z + pz * q2.y - q0.x;
    float l1 = px * q1.x + py * q1.w + pz * q2.z - q0.y;
    float l2 = px * q1.y + py * q2.x + pz * q2.w - q0.z;
    float t0 = l0 * q3.x, t1 = l1 * q3.y, t2 = l2 * q3.z;
    float s0 = t0 * t0 + 1e-8f;
    float s1 = t1 * t1 + 1e-8f;
    float s2 = t2 * t2 + 1e-8f;
    float f = __powf(__powf(s0, q4.y) + __powf(s1, q4.y), q4.z) + __powf(s2, q4.x);
    float a = q3.w * __expf(-0.5f * f);
    density += a;
    float sem[NC];
    *(float4*)(sem + 0)  = q[5];
    *(float4*)(sem + 4)  = q[6];
    *(float4*)(sem + 8)  = q[7];
    *(float4*)(sem + 12) = q[8];
    sem[16] = fp[(size_t)g * FPS + 36];
#pragma unroll
    for (int c = 0; c < NC; ++c) acc[c] = fmaf(a, sem[c], acc[c]);
    logbin += __logf(1.0f - fminf(a, 1.0f - 1e-4f));
}

// 1 thread per point: check own tile's candidate list (avg ~10), evaluate the
// ~1.3 true hits. Mask-then-process keeps the heavy path off the check loop.
__global__ __launch_bounds__(256)
void gather_kernel(const float* __restrict__ pts,
                   const int4* __restrict__ aabb,
                   const unsigned int* __restrict__ cnt,
                   const unsigned short* __restrict__ list,
                   const float* __restrict__ fp,
                   float* __restrict__ out) {
    int p = blockIdx.x * 256 + threadIdx.x;
    float px = pts[p * 3 + 0], py = pts[p * 3 + 1], pz = pts[p * 3 + 2];
    int ix = (int)floorf((px - PCMINX) / GRIDSZ);
    int iy = (int)floorf((py - PCMINY) / GRIDSZ);
    int iz = (int)floorf((pz - PCMINZ) / GRIDSZ);
    int t = (iy >> TSH) * NTX + (ix >> TSH);

    int n = (int)cnt[t];
    const unsigned short* lst = list + (size_t)t * TCAP;

    float density = 0.0f, logbin = 0.0f;
    float acc[NC];
#pragma unroll
    for (int c = 0; c < NC; ++c) acc[c] = 0.0f;

    for (int base = 0; base < n; base += 64) {
        int m = min(n - base, 64);
        unsigned long long msk = 0ull;
#pragma unroll 4
        for (int k = 0; k < m; ++k) {
            int g = lst[base + k];
            int4 b = aabb[g];
            int in3 = (ix >= (b.x & 0xffff)) & (ix <= (b.x >> 16)) &
                      (iy >= (b.y & 0xffff)) & (iy <= (b.y >> 16)) &
                      (iz >= (b.z & 0xffff)) & (iz <= (b.z >> 16));
            msk |= (unsigned long long)in3 << k;
        }
        while (msk) {
            int k = __builtin_ctzll(msk);
            msk &= msk - 1;
            hit_accum(fp, lst[base + k], px, py, pz, acc, density, logbin);
        }
    }

    float inv = 1.0f / (density + 1e-9f);
#pragma unroll
    for (int c = 0; c < NC; ++c) out[(size_t)p * NC + c] = acc[c] * inv;
    out[(size_t)NP * NC + p] = 1.0f - expf(logbin);
    out[(size_t)NP * NC + NP + p] = density;
}

// ---- fallback (ws too small): monolithic kernel ----
__global__ __launch_bounds__(64)
void agg_kernel_fb(const float* __restrict__ pts,
                   const float* __restrict__ means3D,
                   const float* __restrict__ opas,
                   const float* __restrict__ uu,
                   const float* __restrict__ vv,
                   const float* __restrict__ semantics,
                   const float* __restrict__ scales,
                   const float* __restrict__ rot3D,
                   float* __restrict__ out) {
    int p = blockIdx.x * 64 + threadIdx.x;
    if (p >= NP) return;
    float px = pts[p * 3 + 0], py = pts[p * 3 + 1], pz = pts[p * 3 + 2];
    int pix = (int)floorf((px - PCMINX) / GRIDSZ);
    int piy = (int)floorf((py - PCMINY) / GRIDSZ);
    int piz = (int)floorf((pz - PCMINZ) / GRIDSZ);
    float density = 0.0f, logbin = 0.0f;
    float acc[NC];
#pragma unroll
    for (int c = 0; c < NC; ++c) acc[c] = 0.0f;
    for (int g = 0; g < NG; ++g) {
        float cx = means3D[g * 3 + 0], cy = means3D[g * 3 + 1], cz = means3D[g * 3 + 2];
        int mx = (int)floorf((cx - PCMINX) / GRIDSZ);
        int my = (int)floorf((cy - PCMINY) / GRIDSZ);
        int mz = (int)floorf((cz - PCMINZ) / GRIDSZ);
        float smax = fmaxf(scales[g * 3 + 0], fmaxf(scales[g * 3 + 1], scales[g * 3 + 2]));
        int rad = (int)ceilf(smax * SCALE_MULTC / GRIDSZ);
        rad = rad < 1 ? 1 : rad;
        int cheb = max(abs(pix - mx), max(abs(piy - my), abs(piz - mz)));
        if (cheb <= rad) {
            const float* r = rot3D + (size_t)g * 9;
            float dx = px - cx, dy = py - cy, dz = pz - cz;
            float l0 = dx * r[0] + dy * r[3] + dz * r[6];
            float l1 = dx * r[1] + dy * r[4] + dz * r[7];
            float l2 = dx * r[2] + dy * r[5] + dz * r[8];
            float t0 = l0 / scales[g * 3 + 0], t1 = l1 / scales[g * 3 + 1], t2 = l2 / scales[g * 3 + 2];
            float s0 = t0 * t0 + 1e-8f, s1 = t1 * t1 + 1e-8f, s2 = t2 * t2 + 1e-8f;
            float ie1 = 1.0f / uu[g], ie2 = 1.0f / vv[g], e21 = vv[g] / uu[g];
            float f = powf(powf(s0, ie2) + powf(s1, ie2), e21) + powf(s2, ie1);
            float a = opas[g] * expf(-0.5f * f);
            density += a;
            const float* sg = semantics + (size_t)g * NC;
#pragma unroll
            for (int c = 0; c < NC; ++c) acc[c] = fmaf(a, sg[c], acc[c]);
            logbin += log1pf(-fminf(a, 1.0f - 1e-4f));
        }
    }
    float inv = 1.0f / (density + 1e-9f);
#pragma unroll
    for (int c = 0; c < NC; ++c) out[(size_t)p * NC + c] = acc[c] * inv;
    out[(size_t)NP * NC + p] = 1.0f - expf(logbin);
    out[(size_t)NP * NC + NP + p] = density;
}

extern "C" void kernel_launch(void* const* d_in, const int* in_sizes, int n_in,
                              void* d_out, int out_size, void* d_ws, size_t ws_size,
                              hipStream_t stream) {
    const float* pts       = (const float*)d_in[0];
    const float* means3D   = (const float*)d_in[1];
    const float* opas      = (const float*)d_in[2];
    const float* uu        = (const float*)d_in[3];
    const float* vv        = (const float*)d_in[4];
    const float* semantics = (const float*)d_in[5];
    const float* scales    = (const float*)d_in[6];
    const float* rot3D     = (const float*)d_in[7];
    float* out = (float*)d_out;

    size_t fpBytes   = (size_t)NG * FPS * sizeof(float);            // 327,680
    size_t aabbOff   = fpBytes;
    size_t aabbBytes = (size_t)NG * sizeof(int4);                   // 32,768
    size_t cntOff    = aabbOff + aabbBytes;
    size_t cntBytes  = ((size_t)NTILE * sizeof(unsigned int) + 63) & ~(size_t)63;
    size_t listOff   = cntOff + cntBytes;
    size_t listBytes = (size_t)NTILE * TCAP * sizeof(unsigned short); // 160,000
    size_t need = listOff + listBytes;                              // ~523 KB

    if (ws_size >= need) {
        float* fp = (float*)d_ws;
        int4* aabb = (int4*)((char*)d_ws + aabbOff);
        unsigned int* cnt = (unsigned int*)((char*)d_ws + cntOff);
        unsigned short* list = (unsigned short*)((char*)d_ws + listOff);
        prep_kernel<<<NG / 64, 64, 0, stream>>>(means3D, opas, uu, vv, scales, rot3D,
                                                semantics, aabb, fp);
        tile_kernel<<<NTILE, 64, 0, stream>>>(aabb, cnt, list);
        gather_kernel<<<NP / 256, 256, 0, stream>>>(pts, aabb, cnt, list, fp, out);
    } else {
        agg_kernel_fb<<<NP / 64, 64, 0, stream>>>(pts, means3D, opas, uu, vv, semantics,
                                                  scales, rot3D, out);
    }
}

// Round 7
// 46.728 us; speedup vs baseline: 4.2053x; 1.0536x over previous
//
#include <hip/hip_runtime.h>
#include <math.h>

#define NP 16384
#define NG 2048
#define NC 17

#define TSH 3       // tile = 8x8 voxels in (x,y)
#define NTX 25
#define NTY 25
#define NTILE (NTX * NTY)
#define TCAP 128    // max prims per tile list (expected mean ~12, max ~35)

#define GRIDSZ 0.4f
#define PCMINX -40.0f
#define PCMINY -40.0f
#define PCMINZ -1.0f
#define SCALE_MULTC 3.0f

__device__ __forceinline__ void prim_voxel(const float* __restrict__ means3D,
                                           const float* __restrict__ scales, int g,
                                           int& vx, int& vy, int& vz, int& rad) {
    float mx = means3D[g * 3 + 0], my = means3D[g * 3 + 1], mz = means3D[g * 3 + 2];
    float sx = scales[g * 3 + 0], sy = scales[g * 3 + 1], sz = scales[g * 3 + 2];
    vx = (int)floorf((mx - PCMINX) / GRIDSZ);
    vy = (int)floorf((my - PCMINY) / GRIDSZ);
    vz = (int)floorf((mz - PCMINZ) / GRIDSZ);
    float smax = fmaxf(sx, fmaxf(sy, sz));
    rad = (int)ceilf(smax * SCALE_MULTC / GRIDSZ);
    if (rad < 1) rad = 1;
}

// One wave per tile: scan all prims, ballot-compact overlapping prims in
// ascending-g order. Deterministic: no atomics, cnt always overwritten, no
// memset needed, list order fixed.
__global__ __launch_bounds__(64)
void bin_kernel(const float* __restrict__ means3D,
                const float* __restrict__ scales,
                unsigned int* __restrict__ cnt,
                unsigned short* __restrict__ list) {
    int t = blockIdx.x;
    int lane = threadIdx.x;
    int tx = t % NTX, ty = t / NTX;
    unsigned short* lst = list + (size_t)t * TCAP;
    unsigned cl = 0;
    for (int base = 0; base < NG; base += 64) {
        int g = base + lane;
        int vx, vy, vz, rad;
        prim_voxel(means3D, scales, g, vx, vy, vz, rad);
        // arithmetic >> on possibly-negative (vx-rad) is floor-div: correct
        bool ov = (((vx - rad) >> TSH) <= tx) & (((vx + rad) >> TSH) >= tx) &
                  (((vy - rad) >> TSH) <= ty) & (((vy + rad) >> TSH) >= ty);
        unsigned long long bal = __ballot(ov);
        if (ov) {
            int pos = cl + (int)__popcll(bal & ((1ull << lane) - 1ull));
            if (pos < TCAP) lst[pos] = (unsigned short)g;
        }
        cl += (unsigned)__popcll(bal);
    }
    if (lane == 0) cnt[t] = min(cl, (unsigned)TCAP);
}

__device__ __forceinline__ void hit_accum(const float* __restrict__ means3D,
                                          const float* __restrict__ opas,
                                          const float* __restrict__ uu,
                                          const float* __restrict__ vv,
                                          const float* __restrict__ semantics,
                                          const float* __restrict__ scales,
                                          const float* __restrict__ rot3D,
                                          int g, float px, float py, float pz,
                                          float* acc, float& density, float& logbin) {
    const float* r = rot3D + (size_t)g * 9;
    float dx = px - means3D[g * 3 + 0];
    float dy = py - means3D[g * 3 + 1];
    float dz = pz - means3D[g * 3 + 2];
    float l0 = dx * r[0] + dy * r[3] + dz * r[6];
    float l1 = dx * r[1] + dy * r[4] + dz * r[7];
    float l2 = dx * r[2] + dy * r[5] + dz * r[8];
    float t0 = l0 / scales[g * 3 + 0];
    float t1 = l1 / scales[g * 3 + 1];
    float t2 = l2 / scales[g * 3 + 2];
    float s0 = t0 * t0 + 1e-8f;
    float s1 = t1 * t1 + 1e-8f;
    float s2 = t2 * t2 + 1e-8f;
    float ie1 = 1.0f / uu[g];
    float ie2 = 1.0f / vv[g];
    float e21 = vv[g] * ie1;
    float f = __powf(__powf(s0, ie2) + __powf(s1, ie2), e21) + __powf(s2, ie1);
    float a = opas[g] * __expf(-0.5f * f);
    density += a;
    const float* sg = semantics + (size_t)g * NC;
#pragma unroll
    for (int c = 0; c < NC; ++c) acc[c] = fmaf(a, sg[c], acc[c]);
    logbin += __logf(1.0f - fminf(a, 1.0f - 1e-4f));
}

// 1 thread per point: check own tile's candidate list (avg ~12) with the exact
// Chebyshev test, mask-then-process, evaluate ~1.2 true hits from the original
// input arrays (all L2-resident).
__global__ __launch_bounds__(64)
void gather_kernel(const float* __restrict__ pts,
                   const float* __restrict__ means3D,
                   const float* __restrict__ opas,
                   const float* __restrict__ uu,
                   const float* __restrict__ vv,
                   const float* __restrict__ semantics,
                   const float* __restrict__ scales,
                   const float* __restrict__ rot3D,
                   const unsigned int* __restrict__ cnt,
                   const unsigned short* __restrict__ list,
                   float* __restrict__ out) {
    int p = blockIdx.x * 64 + threadIdx.x;
    float px = pts[p * 3 + 0], py = pts[p * 3 + 1], pz = pts[p * 3 + 2];
    int ix = (int)floorf((px - PCMINX) / GRIDSZ);
    int iy = (int)floorf((py - PCMINY) / GRIDSZ);
    int iz = (int)floorf((pz - PCMINZ) / GRIDSZ);
    int t = (iy >> TSH) * NTX + (ix >> TSH);

    int n = (int)cnt[t];
    const unsigned short* lst = list + (size_t)t * TCAP;

    // pass 1: branchless exact Chebyshev mask over candidates
    unsigned long long msk0 = 0ull, msk1 = 0ull;
#pragma unroll 4
    for (int k = 0; k < n; ++k) {
        int g = lst[k];
        int vx, vy, vz, rad;
        prim_voxel(means3D, scales, g, vx, vy, vz, rad);
        int cheb = max(max(abs(ix - vx), abs(iy - vy)), abs(iz - vz));
        unsigned long long bit = (unsigned long long)(cheb <= rad);
        if (k < 64) msk0 |= bit << k;
        else        msk1 |= bit << (k - 64);
    }

    float density = 0.0f, logbin = 0.0f;
    float acc[NC];
#pragma unroll
    for (int c = 0; c < NC; ++c) acc[c] = 0.0f;

    // pass 2: process only true hits
    while (msk0) {
        int k = __builtin_ctzll(msk0);
        msk0 &= msk0 - 1;
        hit_accum(means3D, opas, uu, vv, semantics, scales, rot3D,
                  lst[k], px, py, pz, acc, density, logbin);
    }
    while (msk1) {
        int k = __builtin_ctzll(msk1);
        msk1 &= msk1 - 1;
        hit_accum(means3D, opas, uu, vv, semantics, scales, rot3D,
                  lst[64 + k], px, py, pz, acc, density, logbin);
    }

    float inv = 1.0f / (density + 1e-9f);
#pragma unroll
    for (int c = 0; c < NC; ++c) out[(size_t)p * NC + c] = acc[c] * inv;
    out[(size_t)NP * NC + p] = 1.0f - expf(logbin);
    out[(size_t)NP * NC + NP + p] = density;
}

// ---- fallback (ws too small): monolithic kernel ----
__global__ __launch_bounds__(64)
void agg_kernel_fb(const float* __restrict__ pts,
                   const float* __restrict__ means3D,
                   const float* __restrict__ opas,
                   const float* __restrict__ uu,
                   const float* __restrict__ vv,
                   const float* __restrict__ semantics,
                   const float* __restrict__ scales,
                   const float* __restrict__ rot3D,
                   float* __restrict__ out) {
    int p = blockIdx.x * 64 + threadIdx.x;
    if (p >= NP) return;
    float px = pts[p * 3 + 0], py = pts[p * 3 + 1], pz = pts[p * 3 + 2];
    int pix = (int)floorf((px - PCMINX) / GRIDSZ);
    int piy = (int)floorf((py - PCMINY) / GRIDSZ);
    int piz = (int)floorf((pz - PCMINZ) / GRIDSZ);
    float density = 0.0f, logbin = 0.0f;
    float acc[NC];
#pragma unroll
    for (int c = 0; c < NC; ++c) acc[c] = 0.0f;
    for (int g = 0; g < NG; ++g) {
        int vx, vy, vz, rad;
        prim_voxel(means3D, scales, g, vx, vy, vz, rad);
        int cheb = max(abs(pix - vx), max(abs(piy - vy), abs(piz - vz)));
        if (cheb <= rad) {
            hit_accum(means3D, opas, uu, vv, semantics, scales, rot3D,
                      g, px, py, pz, acc, density, logbin);
        }
    }
    float inv = 1.0f / (density + 1e-9f);
#pragma unroll
    for (int c = 0; c < NC; ++c) out[(size_t)p * NC + c] = acc[c] * inv;
    out[(size_t)NP * NC + p] = 1.0f - expf(logbin);
    out[(size_t)NP * NC + NP + p] = density;
}

extern "C" void kernel_launch(void* const* d_in, const int* in_sizes, int n_in,
                              void* d_out, int out_size, void* d_ws, size_t ws_size,
                              hipStream_t stream) {
    const float* pts       = (const float*)d_in[0];
    const float* means3D   = (const float*)d_in[1];
    const float* opas      = (const float*)d_in[2];
    const float* uu        = (const float*)d_in[3];
    const float* vv        = (const float*)d_in[4];
    const float* semantics = (const float*)d_in[5];
    const float* scales    = (const float*)d_in[6];
    const float* rot3D     = (const float*)d_in[7];
    float* out = (float*)d_out;

    size_t cntBytes  = ((size_t)NTILE * sizeof(unsigned int) + 127) & ~(size_t)127; // 2.6 KB
    size_t listBytes = (size_t)NTILE * TCAP * sizeof(unsigned short);               // 160 KB
    size_t need = cntBytes + listBytes;

    if (ws_size >= need) {
        unsigned int* cnt = (unsigned int*)d_ws;
        unsigned short* list = (unsigned short*)((char*)d_ws + cntBytes);
        bin_kernel<<<NTILE, 64, 0, stream>>>(means3D, scales, cnt, list);
        gather_kernel<<<NP / 64, 64, 0, stream>>>(pts, means3D, opas, uu, vv, semantics,
                                                  scales, rot3D, cnt, list, out);
    } else {
        agg_kernel_fb<<<NP / 64, 64, 0, stream>>>(pts, means3D, opas, uu, vv, semantics,
                                                  scales, rot3D, out);
    }
}